// Round 17
// baseline (2018.822 us; speedup 1.0000x reference)
//
#include <hip/hip_runtime.h>
#include <cstdint>
#include <cstddef>

#define B_   64
#define T_   2048
#define C_   64
#define H_   256
#define G3_  768    // 3*H
#define HOR_ 96

typedef _Float16 h2 __attribute__((ext_vector_type(2)));
typedef _Float16 h8 __attribute__((ext_vector_type(8)));
typedef _Float16 f16x8 __attribute__((ext_vector_type(8)));
typedef float f32x4 __attribute__((ext_vector_type(4)));

// ---------------------------------------------------------------------------
// K0: zero spk/gx flags (ws re-poisoned 0xAA each call). 2048 ints.
// ---------------------------------------------------------------------------
__global__ void k_zero(int* __restrict__ flags) {
  flags[threadIdx.x] = 0;
  flags[threadIdx.x + 1024] = 0;
}

// ---------------------------------------------------------------------------
// FULLY FUSED: cur + LIF + gx-GEMM + GRU scan + head in ONE kernel.
// 256 blocks x 256 thr, all co-resident (1/CU). VGPR budget = 256 (allocator
// gives 2-blocks/CU budgets: 256thr->256 regs — confirmed round 16).
//  blocks 0..63   : GRU consumer, batch b (round-16: 3 rows/thread, full K,
//                   int8 sdot4, zero reduction, 1 barrier/step).
//  blocks 64..255 : producers, 3 per batch. Producer 0 ALSO computes cur
//                   (k_cur source-verbatim -> bit-identical spikes) + LIF
//                   per 128-t chunk before the MFMA tile, so the whole
//                   pre-work pipeline overlaps the scan (round-17 change:
//                   removes ~150 us of serial k_cur/k_lif + launches).
// Handoff: spkf[b*16+mt] (producer 0 -> producers 1,2), gxf[b*16+mt]
// (3 producers -> consumer). RELEASE/ACQUIRE at AGENT scope (cross-XCD G16).
// 256 blocks <= 256 CUs -> co-resident, deadlock-free (prod 0 never waits;
// prods 1,2 wait only on prod 0; consumer waits only on producers).
// ---------------------------------------------------------------------------
#define GM 128
#define GN 128
#define AKP 40   // padded K-chunk stride (halves)
#define CTP 136  // C-transpose row stride (halves)
#define DQ_ (0.0625f / (127.0f * 127.0f))
__global__ __launch_bounds__(256) void k_fused(
    const float* __restrict__ x, unsigned char* __restrict__ spk,
    const float* __restrict__ wih, const float* __restrict__ bih,
    _Float16* __restrict__ gx, const float* __restrict__ whh,
    const float* __restrict__ bhh, const float* __restrict__ head_w,
    const float* __restrict__ head_b, float* __restrict__ out,
    const float* __restrict__ snn_w, const float* __restrict__ snn_b,
    int* __restrict__ gxf, int* __restrict__ spkf) {
  alignas(16) __shared__ _Float16 Ah[GM * AKP];  // 10 KB (producer; cur x-stage alias)
  alignas(16) __shared__ _Float16 Bh[GN * AKP];  // 10 KB (producer)
  alignas(16) __shared__ _Float16 Ct[GM * CTP];  // 34 KB (producer)
  alignas(16) __shared__ int hq[2][64];          // 512 B (consumer)
  __shared__ float hbuf32[H_];                   // 1 KB (consumer)

  const int tid = threadIdx.x;
  const int lane = tid & 63;

  if (blockIdx.x >= 64) {
    // ===================== PRODUCER =====================
    const int pidx = blockIdx.x - 64;
    const int bb = pidx / 3;
    const int pp = pidx - bb * 3;
    const int wave = tid >> 6;        // 0..3
    const int ln = lane & 15;
    const int qd = lane >> 4;
    const int wm = (wave & 1) * 64;
    const int wn = ((wave >> 1) & 1) * 64;

    // producer 0: snn weight row (k_cur-identical layout) + LIF carry
    float snw[C_];
    float snb = 0.f, mem = 0.f;
    if (pp == 0) {
      const float4* wp = (const float4*)(snn_w + (size_t)tid * C_);
#pragma unroll
      for (int q = 0; q < C_ / 4; q++) {
        float4 v = wp[q];
        snw[4 * q + 0] = v.x; snw[4 * q + 1] = v.y;
        snw[4 * q + 2] = v.z; snw[4 * q + 3] = v.w;
      }
      snb = snn_b[tid];
    }

    for (int mt = 0; mt < 16; mt++) {
      const int t0g = bb * 2048 + mt * 128;   // global row (b*T + t)

      if (pp == 0) {
        // ---- cur + LIF for this chunk (4 sub-blocks of 32 t) ----
        float* xstage = (float*)Ah;  // 8 KB of the 10 KB Ah region
        for (int s = 0; s < 4; s++) {
          __syncthreads();
#pragma unroll
          for (int i = 0; i < 2; i++) {
            int idx = tid + i * 256;        // 0..511 float4s
            int r = idx >> 4;               // 0..31
            int c4 = (idx & 15) * 4;
            *(float4*)&xstage[r * C_ + c4] =
                *(const float4*)(x + (size_t)(t0g + s * 32 + r) * C_ + c4);
          }
          __syncthreads();
          // cur: k_cur source-verbatim (bit-identical -> identical spikes)
          float curv[32];
#pragma unroll
          for (int t = 0; t < 32; t++) {
            const float4* xrow = (const float4*)(xstage + t * C_);
            float a0 = 0.f, a1 = 0.f;
#pragma unroll
            for (int q = 0; q < C_ / 4; q += 2) {
              float4 v0 = xrow[q];
              float4 v1 = xrow[q + 1];
              a0 += snw[4 * q + 0] * v0.x + snw[4 * q + 1] * v0.y +
                    snw[4 * q + 2] * v0.z + snw[4 * q + 3] * v0.w;
              a1 += snw[4 * q + 4] * v1.x + snw[4 * q + 5] * v1.y +
                    snw[4 * q + 6] * v1.z + snw[4 * q + 7] * v1.w;
            }
            curv[t] = a0 + a1 + snb;
          }
          // LIF scan (k_lif-identical), spk byte stores (row-coalesced)
          unsigned char* spb = spk + (size_t)(t0g + s * 32) * H_ + tid;
#pragma unroll
          for (int t = 0; t < 32; t++) {
            float reset = (mem > 1.0f) ? 1.0f : 0.0f;
            mem = 0.9f * mem + curv[t] - reset;
            spb[(size_t)t * H_] = (mem > 1.0f) ? (unsigned char)1 : (unsigned char)0;
          }
        }
        __syncthreads();  // vmcnt drained: spk visible before flag
        if (tid == 0)
          __hip_atomic_fetch_add(&spkf[bb * 16 + mt], 1, __ATOMIC_RELEASE,
                                 __HIP_MEMORY_SCOPE_AGENT);
      } else {
        if (tid == 0) {
          while (__hip_atomic_load(&spkf[bb * 16 + mt], __ATOMIC_ACQUIRE,
                                   __HIP_MEMORY_SCOPE_AGENT) < 1)
            __builtin_amdgcn_s_sleep(8);
        }
        __syncthreads();
      }

      // ---- gx MFMA tile (round-11/16, unchanged) ----
      const int m0 = t0g;
      for (int nh = 0; nh < 2; nh++) {
        const int n0 = pp * 256 + nh * 128;
        f32x4 acc[4][4] = {};
        for (int kc = 0; kc < 10; kc++) {
          const int k0 = kc * 32;
          if (k0 < 64) {
#pragma unroll
            for (int i = 0; i < 4; i++) {
              int idx = tid + i * 256;
              int r = idx >> 3;
              int c4 = (idx & 7) * 4;
              float4 v = *(const float4*)(x + (size_t)(m0 + r) * C_ + k0 + c4);
              h2 lo, hi;
              lo.x = (_Float16)v.x; lo.y = (_Float16)v.y;
              hi.x = (_Float16)v.z; hi.y = (_Float16)v.w;
              h2* d = (h2*)&Ah[r * AKP + c4];
              d[0] = lo; d[1] = hi;
            }
          } else {
#pragma unroll
            for (int i = 0; i < 4; i++) {
              int idx = tid + i * 256;
              int r = idx >> 3;
              int c4 = (idx & 7) * 4;
              uchar4 u = *(const uchar4*)(spk + (size_t)(m0 + r) * H_ + (k0 - 64) + c4);
              h2 lo, hi;
              lo.x = (_Float16)(int)u.x; lo.y = (_Float16)(int)u.y;
              hi.x = (_Float16)(int)u.z; hi.y = (_Float16)(int)u.w;
              h2* d = (h2*)&Ah[r * AKP + c4];
              d[0] = lo; d[1] = hi;
            }
          }
#pragma unroll
          for (int i = 0; i < 4; i++) {
            int idx = tid + i * 256;
            int r = idx >> 3;
            int c4 = (idx & 7) * 4;
            float4 v = *(const float4*)(wih + (size_t)(n0 + r) * 320 + k0 + c4);
            h2 lo, hi;
            lo.x = (_Float16)v.x; lo.y = (_Float16)v.y;
            hi.x = (_Float16)v.z; hi.y = (_Float16)v.w;
            h2* d = (h2*)&Bh[r * AKP + c4];
            d[0] = lo; d[1] = hi;
          }
          __syncthreads();
          {
            f16x8 a[4], bbf[4];
#pragma unroll
            for (int mtl = 0; mtl < 4; mtl++)
              a[mtl] = *(const f16x8*)&Ah[(wm + mtl * 16 + ln) * AKP + qd * 8];
#pragma unroll
            for (int nt = 0; nt < 4; nt++)
              bbf[nt] = *(const f16x8*)&Bh[(wn + nt * 16 + ln) * AKP + qd * 8];
#pragma unroll
            for (int mtl = 0; mtl < 4; mtl++)
#pragma unroll
              for (int nt = 0; nt < 4; nt++)
                acc[mtl][nt] = __builtin_amdgcn_mfma_f32_16x16x32_f16(
                    a[mtl], bbf[nt], acc[mtl][nt], 0, 0, 0);
          }
          __syncthreads();
        }
        {
          float bias[4];
#pragma unroll
          for (int nt = 0; nt < 4; nt++) bias[nt] = bih[n0 + wn + nt * 16 + ln];
#pragma unroll
          for (int mtl = 0; mtl < 4; mtl++)
#pragma unroll
            for (int nt = 0; nt < 4; nt++) {
              int n = wn + nt * 16 + ln;
#pragma unroll
              for (int r = 0; r < 4; r++) {
                int m = wm + mtl * 16 + qd * 4 + r;
                Ct[m * CTP + n] = (_Float16)(acc[mtl][nt][r] + bias[nt]);
              }
            }
        }
        __syncthreads();
#pragma unroll
        for (int i = 0; i < 8; i++) {
          int idx = tid + i * 256;
          int r = idx >> 4;
          int c = (idx & 15) * 8;
          *(h8*)(gx + (size_t)(m0 + r) * G3_ + n0 + c) = *(const h8*)&Ct[r * CTP + c];
        }
        __syncthreads();  // stores drained before flag / Ct reuse
      }
      if (tid == 0)
        __hip_atomic_fetch_add(&gxf[bb * 16 + mt], 1, __ATOMIC_RELEASE,
                               __HIP_MEMORY_SCOPE_AGENT);
    }
    return;
  }

  // ========== CONSUMER (round-16 exact): 3 rows/thread, zero reduction ==========
  const int b = blockIdx.x;
  const int j = tid;   // 0..255: owns whh rows {j, j+256, j+512}, full K

  int wr[64], wz[64], wn[64];
  {
    const float qs = 2032.0f;  // 127 / 0.0625
    const float4* p0 = (const float4*)(whh + (size_t)j * H_);
    const float4* p1 = (const float4*)(whh + (size_t)(H_ + j) * H_);
    const float4* p2 = (const float4*)(whh + (size_t)(2 * H_ + j) * H_);
#pragma unroll
    for (int q = 0; q < 64; q++) {
      float4 a = p0[q];
      wr[q] = ((int)rintf(a.x * qs) & 255) | (((int)rintf(a.y * qs) & 255) << 8) |
              (((int)rintf(a.z * qs) & 255) << 16) | (((int)rintf(a.w * qs) & 255) << 24);
      float4 c = p1[q];
      wz[q] = ((int)rintf(c.x * qs) & 255) | (((int)rintf(c.y * qs) & 255) << 8) |
              (((int)rintf(c.z * qs) & 255) << 16) | (((int)rintf(c.w * qs) & 255) << 24);
      float4 d = p2[q];
      wn[q] = ((int)rintf(d.x * qs) & 255) | (((int)rintf(d.y * qs) & 255) << 8) |
              (((int)rintf(d.z * qs) & 255) << 16) | (((int)rintf(d.w * qs) & 255) << 24);
    }
  }
  const float br_ = bhh[j], bz_ = bhh[H_ + j], bn_ = bhh[2 * H_ + j];

  if (tid < 128) ((int*)hq)[tid] = 0;
  float hj = 0.f;
  __syncthreads();

  const _Float16* gxb = gx + (size_t)b * T_ * G3_;
  int p = 0;
  for (int mt = 0; mt < 16; mt++) {
    if (tid == 0) {
      while (__hip_atomic_load(&gxf[b * 16 + mt], __ATOMIC_ACQUIRE,
                               __HIP_MEMORY_SCOPE_AGENT) < 3)
        __builtin_amdgcn_s_sleep(8);
    }
    __syncthreads();

    const _Float16* gc = gxb + (size_t)mt * 128 * G3_;
    _Float16 pr = gc[j], pz = gc[H_ + j], pn = gc[2 * H_ + j];

    for (int tt = 0; tt < 128; tt++) {
      float xr = (float)pr, xz = (float)pz, xn = (float)pn;
      if (tt < 127) {
        const _Float16* g = gc + (size_t)(tt + 1) * G3_;
        pr = g[j]; pz = g[H_ + j]; pn = g[2 * H_ + j];
      }

      const int* hb = hq[p];
      int ar0 = 0, ar1 = 0, az0 = 0, az1 = 0, an0 = 0, an1 = 0;
#pragma unroll
      for (int g4 = 0; g4 < 4; g4++) {
#pragma unroll
        for (int cc = 0; cc < 4; cc++) {
          int c = g4 * 4 + cc;                 // 0..15
          int4 hv = *(const int4*)(hb + c * 4);
#pragma unroll
          for (int i = 0; i < 4; i++) {
            int h4 = (i == 0) ? hv.x : (i == 1) ? hv.y : (i == 2) ? hv.z : hv.w;
            int wi = c * 4 + i;                // 0..63
            if (wi & 1) {
              ar1 = __builtin_amdgcn_sdot4(wr[wi], h4, ar1, false);
              az1 = __builtin_amdgcn_sdot4(wz[wi], h4, az1, false);
              an1 = __builtin_amdgcn_sdot4(wn[wi], h4, an1, false);
            } else {
              ar0 = __builtin_amdgcn_sdot4(wr[wi], h4, ar0, false);
              az0 = __builtin_amdgcn_sdot4(wz[wi], h4, az0, false);
              an0 = __builtin_amdgcn_sdot4(wn[wi], h4, an0, false);
            }
          }
        }
        __builtin_amdgcn_sched_barrier(2 | 4 | 16 | 32 | 64);  // anti-hoist
      }
      int ar = ar0 + ar1, az = az0 + az1, an = an0 + an1;

      float r = 1.f / (1.f + __expf(-(xr + (float)ar * DQ_ + br_)));
      float z = 1.f / (1.f + __expf(-(xz + (float)az * DQ_ + bz_)));
      float pre = xn + r * ((float)an * DQ_ + bn_);
      float e = __expf(2.f * pre);          // tanh(x) = 1 - 2/(e^{2x}+1)
      float n = 1.f - 2.f / (e + 1.f);
      hj = (1.f - z) * n + z * hj;

      ((char*)hq[p ^ 1])[j] = (char)(int)rintf(hj * 127.0f);
      p ^= 1;
      __syncthreads();   // the ONLY barrier per step
    }
  }

  hbuf32[j] = hj;
  __syncthreads();

  if (tid < HOR_) {
    const float4* hw = (const float4*)(head_w + (size_t)tid * H_);
    const float4* hv4 = (const float4*)hbuf32;
    float acc = head_b[tid];
#pragma unroll
    for (int q = 0; q < H_ / 4; q++) {
      float4 w4 = hw[q];
      float4 v4 = hv4[q];
      acc += w4.x * v4.x + w4.y * v4.y + w4.z * v4.z + w4.w * v4.w;
    }
    out[(size_t)b * HOR_ + tid] = acc;
  }
}

// ---------------------------------------------------------------------------
extern "C" void kernel_launch(void* const* d_in, const int* in_sizes, int n_in,
                              void* d_out, int out_size, void* d_ws, size_t ws_size,
                              hipStream_t stream) {
  const float* x      = (const float*)d_in[0];
  const float* snn_w  = (const float*)d_in[1];
  const float* snn_b  = (const float*)d_in[2];
  const float* wih    = (const float*)d_in[3];
  const float* whh    = (const float*)d_in[4];
  const float* bih    = (const float*)d_in[5];
  const float* bhh    = (const float*)d_in[6];
  const float* head_w = (const float*)d_in[7];
  const float* head_b = (const float*)d_in[8];
  float* out = (float*)d_out;

  // ws layout (235 MB + 8 KB flags):
  //   [0, 201326592)          gx fp16 [131072,768]
  //   [201326592, 234881024)  spk u8 [131072,256]
  //   [234881024, +4096)      gxf int[1024]
  //   [234885120, +4096)      spkf int[1024]
  char* ws = (char*)d_ws;
  _Float16* gx = (_Float16*)ws;
  unsigned char* spk = (unsigned char*)(ws + (size_t)201326592);
  int* gxf  = (int*)(ws + (size_t)234881024);
  int* spkf = (int*)(ws + (size_t)234885120);

  k_zero<<<1, 1024, 0, stream>>>(gxf);
  k_fused<<<dim3(256), 256, 0, stream>>>(x, spk, wih, bih, gx, whh, bhh,
                                         head_w, head_b, out, snn_w, snn_b,
                                         gxf, spkf);
}

// Round 18
// 1846.682 us; speedup vs baseline: 1.0932x; 1.0932x over previous
//
#include <hip/hip_runtime.h>
#include <cstdint>
#include <cstddef>

#define B_   64
#define T_   2048
#define C_   64
#define H_   256
#define G3_  768    // 3*H
#define HOR_ 96

typedef _Float16 h2 __attribute__((ext_vector_type(2)));
typedef _Float16 h8 __attribute__((ext_vector_type(8)));
typedef _Float16 f16x8 __attribute__((ext_vector_type(8)));
typedef float f32x4 __attribute__((ext_vector_type(4)));

// ---------------------------------------------------------------------------
// K1: cur[b,t,h] = sum_c x[b,t,c]*snn_w[h,c] + snn_b[h]   (fp32)
// Block (0,0) also zeroes the producer->consumer flags.
// ---------------------------------------------------------------------------
#define K1_TT 128
__global__ __launch_bounds__(256) void k_cur(const float* __restrict__ x,
                                             const float* __restrict__ w,
                                             const float* __restrict__ bias,
                                             float* __restrict__ cur,
                                             int* __restrict__ flags) {
  __shared__ float xs[K1_TT * C_];  // 32 KB
  const int b = blockIdx.x;
  const int t0 = blockIdx.y * K1_TT;
  const int tid = threadIdx.x;

  if (b == 0 && blockIdx.y == 0) {
#pragma unroll
    for (int i = 0; i < 4; i++) flags[tid + i * 256] = 0;
  }

  const float4* xsrc = (const float4*)(x + ((size_t)b * T_ + t0) * C_);
  float4* xdst = (float4*)xs;
#pragma unroll
  for (int i = 0; i < (K1_TT * C_ / 4) / 256; i++)
    xdst[tid + i * 256] = xsrc[tid + i * 256];

  float wr[C_];
  const float4* wp = (const float4*)(w + (size_t)tid * C_);
#pragma unroll
  for (int q = 0; q < C_ / 4; q++) {
    float4 v = wp[q];
    wr[4 * q + 0] = v.x; wr[4 * q + 1] = v.y;
    wr[4 * q + 2] = v.z; wr[4 * q + 3] = v.w;
  }
  const float bb = bias[tid];
  __syncthreads();

  for (int t = 0; t < K1_TT; t++) {
    const float4* xrow = (const float4*)(xs + t * C_);
    float a0 = 0.f, a1 = 0.f;
#pragma unroll
    for (int q = 0; q < C_ / 4; q += 2) {
      float4 v0 = xrow[q];
      float4 v1 = xrow[q + 1];
      a0 += wr[4 * q + 0] * v0.x + wr[4 * q + 1] * v0.y +
            wr[4 * q + 2] * v0.z + wr[4 * q + 3] * v0.w;
      a1 += wr[4 * q + 4] * v1.x + wr[4 * q + 5] * v1.y +
            wr[4 * q + 6] * v1.z + wr[4 * q + 7] * v1.w;
    }
    cur[((size_t)b * T_ + t0 + t) * H_ + tid] = a0 + a1 + bb;
  }
}

// ---------------------------------------------------------------------------
// K2: LIF scan per (b,h). Spikes stored as u8 (exact). unroll 32 keeps ~32
// loads in flight (round-14 fix: was latency-bound at unroll 8).
// ---------------------------------------------------------------------------
__global__ __launch_bounds__(64) void k_lif(const float* __restrict__ cur,
                                            unsigned char* __restrict__ spk) {
  const int b = blockIdx.x >> 2;
  const int h = ((blockIdx.x & 3) << 6) + threadIdx.x;
  const float* cp = cur + (size_t)b * T_ * H_ + h;
  unsigned char* sp = spk + (size_t)b * T_ * H_ + h;
  float mem = 0.f;
#pragma unroll 32
  for (int t = 0; t < T_; t++) {
    float c = cp[(size_t)t * H_];
    float reset = (mem > 1.0f) ? 1.0f : 0.0f;  // from previous mem
    mem = 0.9f * mem + c - reset;              // THR = 1
    sp[(size_t)t * H_] = (mem > 1.0f) ? (unsigned char)1 : (unsigned char)0;
  }
}

// ---------------------------------------------------------------------------
// K3+K4 FUSED — 256 threads/block. Allocator gives 2-blocks/CU budgets
// (512->128, 768->84, 1024->64, 256->256 VGPRs — confirmed round 16), so a
// 256-thr consumer holds ALL THREE gate rows of j (int8, full K) = 192
// dwords in ARCH VGPRs: no shfl reduction, gates in-register, 1 barrier/step.
//  blocks 0..63   : GRU consumer, batch b.
//  blocks 64..255 : gx producers — 3 per batch (round-11 MFMA tile).
// Handoff: flags[b*16+mt] RELEASE/AGENT add, ACQUIRE spin per 128-step
// chunk. 256 blocks <= 256 CUs -> co-resident, deadlock-free.
// Round-17 lesson (reverted): folding cur+LIF into producer 0 slowed the
// fused kernel 1628->2000 us (serial LIF on the producer critical path +
// low-occupancy cur loop) — keep pre-work as separate full-device kernels.
// ---------------------------------------------------------------------------
#define GM 128
#define GN 128
#define AKP 40   // padded K-chunk stride (halves)
#define CTP 136  // C-transpose row stride (halves)
#define DQ_ (0.0625f / (127.0f * 127.0f))
__global__ __launch_bounds__(256) void k_fused(
    const float* __restrict__ x, const unsigned char* __restrict__ spk,
    const float* __restrict__ wih, const float* __restrict__ bih,
    _Float16* __restrict__ gx, const float* __restrict__ whh,
    const float* __restrict__ bhh, const float* __restrict__ head_w,
    const float* __restrict__ head_b, float* __restrict__ out,
    int* __restrict__ flags) {
  alignas(16) __shared__ _Float16 Ah[GM * AKP];  // 10 KB (producer)
  alignas(16) __shared__ _Float16 Bh[GN * AKP];  // 10 KB (producer)
  alignas(16) __shared__ _Float16 Ct[GM * CTP];  // 34 KB (producer)
  alignas(16) __shared__ int hq[2][64];          // 512 B (consumer)
  __shared__ float hbuf32[H_];                   // 1 KB (consumer)

  const int tid = threadIdx.x;
  const int lane = tid & 63;

  if (blockIdx.x >= 64) {
    // ===================== PRODUCER (round-11 tile, 256 thr) =====================
    const int pidx = blockIdx.x - 64;
    const int bb = pidx / 3;
    const int pp = pidx - bb * 3;
    const int wave = tid >> 6;        // 0..3
    const int ln = lane & 15;
    const int qd = lane >> 4;
    const int wm = (wave & 1) * 64;
    const int wn = ((wave >> 1) & 1) * 64;

    for (int mt = 0; mt < 16; mt++) {
      const int m0 = bb * 2048 + mt * 128;
      for (int nh = 0; nh < 2; nh++) {
        const int n0 = pp * 256 + nh * 128;
        f32x4 acc[4][4] = {};
        for (int kc = 0; kc < 10; kc++) {
          const int k0 = kc * 32;
          if (k0 < 64) {
#pragma unroll
            for (int i = 0; i < 4; i++) {
              int idx = tid + i * 256;
              int r = idx >> 3;
              int c4 = (idx & 7) * 4;
              float4 v = *(const float4*)(x + (size_t)(m0 + r) * C_ + k0 + c4);
              h2 lo, hi;
              lo.x = (_Float16)v.x; lo.y = (_Float16)v.y;
              hi.x = (_Float16)v.z; hi.y = (_Float16)v.w;
              h2* d = (h2*)&Ah[r * AKP + c4];
              d[0] = lo; d[1] = hi;
            }
          } else {
#pragma unroll
            for (int i = 0; i < 4; i++) {
              int idx = tid + i * 256;
              int r = idx >> 3;
              int c4 = (idx & 7) * 4;
              uchar4 u = *(const uchar4*)(spk + (size_t)(m0 + r) * H_ + (k0 - 64) + c4);
              h2 lo, hi;
              lo.x = (_Float16)(int)u.x; lo.y = (_Float16)(int)u.y;
              hi.x = (_Float16)(int)u.z; hi.y = (_Float16)(int)u.w;
              h2* d = (h2*)&Ah[r * AKP + c4];
              d[0] = lo; d[1] = hi;
            }
          }
#pragma unroll
          for (int i = 0; i < 4; i++) {
            int idx = tid + i * 256;
            int r = idx >> 3;
            int c4 = (idx & 7) * 4;
            float4 v = *(const float4*)(wih + (size_t)(n0 + r) * 320 + k0 + c4);
            h2 lo, hi;
            lo.x = (_Float16)v.x; lo.y = (_Float16)v.y;
            hi.x = (_Float16)v.z; hi.y = (_Float16)v.w;
            h2* d = (h2*)&Bh[r * AKP + c4];
            d[0] = lo; d[1] = hi;
          }
          __syncthreads();
          {
            f16x8 a[4], bbf[4];
#pragma unroll
            for (int mtl = 0; mtl < 4; mtl++)
              a[mtl] = *(const f16x8*)&Ah[(wm + mtl * 16 + ln) * AKP + qd * 8];
#pragma unroll
            for (int nt = 0; nt < 4; nt++)
              bbf[nt] = *(const f16x8*)&Bh[(wn + nt * 16 + ln) * AKP + qd * 8];
#pragma unroll
            for (int mtl = 0; mtl < 4; mtl++)
#pragma unroll
              for (int nt = 0; nt < 4; nt++)
                acc[mtl][nt] = __builtin_amdgcn_mfma_f32_16x16x32_f16(
                    a[mtl], bbf[nt], acc[mtl][nt], 0, 0, 0);
          }
          __syncthreads();
        }
        {
          float bias[4];
#pragma unroll
          for (int nt = 0; nt < 4; nt++) bias[nt] = bih[n0 + wn + nt * 16 + ln];
#pragma unroll
          for (int mtl = 0; mtl < 4; mtl++)
#pragma unroll
            for (int nt = 0; nt < 4; nt++) {
              int n = wn + nt * 16 + ln;
#pragma unroll
              for (int r = 0; r < 4; r++) {
                int m = wm + mtl * 16 + qd * 4 + r;
                Ct[m * CTP + n] = (_Float16)(acc[mtl][nt][r] + bias[nt]);
              }
            }
        }
        __syncthreads();
#pragma unroll
        for (int i = 0; i < 8; i++) {
          int idx = tid + i * 256;
          int r = idx >> 4;
          int c = (idx & 15) * 8;
          *(h8*)(gx + (size_t)(m0 + r) * G3_ + n0 + c) = *(const h8*)&Ct[r * CTP + c];
        }
        __syncthreads();  // stores drained before flag / Ct reuse
      }
      if (tid == 0)
        __hip_atomic_fetch_add(&flags[bb * 16 + mt], 1, __ATOMIC_RELEASE,
                               __HIP_MEMORY_SCOPE_AGENT);
    }
    return;
  }

  // ========== CONSUMER: 3 rows/thread, full K, zero reduction ==========
  const int b = blockIdx.x;
  const int j = tid;   // 0..255: owns whh rows {j, j+256, j+512}, full K

  // quantize 3 full rows -> 192 packed i8x4 dwords (arch VGPRs @ 256 budget)
  int wr[64], wz[64], wn[64];
  {
    const float qs = 2032.0f;  // 127 / 0.0625
    const float4* p0 = (const float4*)(whh + (size_t)j * H_);
    const float4* p1 = (const float4*)(whh + (size_t)(H_ + j) * H_);
    const float4* p2 = (const float4*)(whh + (size_t)(2 * H_ + j) * H_);
#pragma unroll
    for (int q = 0; q < 64; q++) {
      float4 a = p0[q];
      wr[q] = ((int)rintf(a.x * qs) & 255) | (((int)rintf(a.y * qs) & 255) << 8) |
              (((int)rintf(a.z * qs) & 255) << 16) | (((int)rintf(a.w * qs) & 255) << 24);
      float4 c = p1[q];
      wz[q] = ((int)rintf(c.x * qs) & 255) | (((int)rintf(c.y * qs) & 255) << 8) |
              (((int)rintf(c.z * qs) & 255) << 16) | (((int)rintf(c.w * qs) & 255) << 24);
      float4 d = p2[q];
      wn[q] = ((int)rintf(d.x * qs) & 255) | (((int)rintf(d.y * qs) & 255) << 8) |
              (((int)rintf(d.z * qs) & 255) << 16) | (((int)rintf(d.w * qs) & 255) << 24);
    }
  }
  const float br_ = bhh[j], bz_ = bhh[H_ + j], bn_ = bhh[2 * H_ + j];

  if (tid < 128) ((int*)hq)[tid] = 0;
  float hj = 0.f;
  __syncthreads();

  const _Float16* gxb = gx + (size_t)b * T_ * G3_;
  int p = 0;
  for (int mt = 0; mt < 16; mt++) {
    if (tid == 0) {
      while (__hip_atomic_load(&flags[b * 16 + mt], __ATOMIC_ACQUIRE,
                               __HIP_MEMORY_SCOPE_AGENT) < 3)
        __builtin_amdgcn_s_sleep(8);
    }
    __syncthreads();

    const _Float16* gc = gxb + (size_t)mt * 128 * G3_;
    _Float16 pr = gc[j], pz = gc[H_ + j], pn = gc[2 * H_ + j];

    for (int tt = 0; tt < 128; tt++) {
      float xr = (float)pr, xz = (float)pz, xn = (float)pn;
      if (tt < 127) {
        const _Float16* g = gc + (size_t)(tt + 1) * G3_;
        pr = g[j]; pz = g[H_ + j]; pn = g[2 * H_ + j];
      }

      // 192 sdot4 over full K; 2 partial accs/gate halve the chain depth.
      // h reads are same-address across the wave -> LDS broadcast.
      const int* hb = hq[p];
      int ar0 = 0, ar1 = 0, az0 = 0, az1 = 0, an0 = 0, an1 = 0;
#pragma unroll
      for (int g4 = 0; g4 < 4; g4++) {
#pragma unroll
        for (int cc = 0; cc < 4; cc++) {
          int c = g4 * 4 + cc;                 // 0..15
          int4 hv = *(const int4*)(hb + c * 4);
#pragma unroll
          for (int i = 0; i < 4; i++) {
            int h4 = (i == 0) ? hv.x : (i == 1) ? hv.y : (i == 2) ? hv.z : hv.w;
            int wi = c * 4 + i;                // 0..63
            if (wi & 1) {
              ar1 = __builtin_amdgcn_sdot4(wr[wi], h4, ar1, false);
              az1 = __builtin_amdgcn_sdot4(wz[wi], h4, az1, false);
              an1 = __builtin_amdgcn_sdot4(wn[wi], h4, an1, false);
            } else {
              ar0 = __builtin_amdgcn_sdot4(wr[wi], h4, ar0, false);
              az0 = __builtin_amdgcn_sdot4(wz[wi], h4, az0, false);
              an0 = __builtin_amdgcn_sdot4(wn[wi], h4, an0, false);
            }
          }
        }
        __builtin_amdgcn_sched_barrier(2 | 4 | 16 | 32 | 64);  // anti-hoist
      }
      int ar = ar0 + ar1, az = az0 + az1, an = an0 + an1;

      // gates fully in-register (thread j owns r/z/n of the same j)
      float r = 1.f / (1.f + __expf(-(xr + (float)ar * DQ_ + br_)));
      float z = 1.f / (1.f + __expf(-(xz + (float)az * DQ_ + bz_)));
      float pre = xn + r * ((float)an * DQ_ + bn_);
      float e = __expf(2.f * pre);          // tanh(x) = 1 - 2/(e^{2x}+1)
      float n = 1.f - 2.f / (e + 1.f);
      hj = (1.f - z) * n + z * hj;

      ((char*)hq[p ^ 1])[j] = (char)(int)rintf(hj * 127.0f);
      p ^= 1;
      __syncthreads();   // the ONLY barrier per step
    }
  }

  hbuf32[j] = hj;
  __syncthreads();

  if (tid < HOR_) {
    const float4* hw = (const float4*)(head_w + (size_t)tid * H_);
    const float4* hv4 = (const float4*)hbuf32;
    float acc = head_b[tid];
#pragma unroll
    for (int q = 0; q < H_ / 4; q++) {
      float4 w4 = hw[q];
      float4 v4 = hv4[q];
      acc += w4.x * v4.x + w4.y * v4.y + w4.z * v4.z + w4.w * v4.w;
    }
    out[(size_t)b * HOR_ + tid] = acc;
  }
}

// ---------------------------------------------------------------------------
extern "C" void kernel_launch(void* const* d_in, const int* in_sizes, int n_in,
                              void* d_out, int out_size, void* d_ws, size_t ws_size,
                              hipStream_t stream) {
  const float* x      = (const float*)d_in[0];
  const float* snn_w  = (const float*)d_in[1];
  const float* snn_b  = (const float*)d_in[2];
  const float* wih    = (const float*)d_in[3];
  const float* whh    = (const float*)d_in[4];
  const float* bih    = (const float*)d_in[5];
  const float* bhh    = (const float*)d_in[6];
  const float* head_w = (const float*)d_in[7];
  const float* head_b = (const float*)d_in[8];
  float* out = (float*)d_out;

  // ws layout (235 MB + 4 KB flags):
  //   [0, 201326592)          gx fp16 [131072,768]
  //   [0, 134217728)          cur fp32 [131072,256] — alias, dead before fused
  //   [201326592, 234881024)  spk u8 [131072,256]
  //   [234881024, 234885120)  flags int[1024]
  char* ws = (char*)d_ws;
  _Float16* gx = (_Float16*)ws;
  float* cur = (float*)ws;
  unsigned char* spk = (unsigned char*)(ws + (size_t)201326592);
  int* flags = (int*)(ws + (size_t)234881024);

  k_cur<<<dim3(B_, T_ / K1_TT), 256, 0, stream>>>(x, snn_w, snn_b, cur, flags);
  k_lif<<<dim3(256), 64, 0, stream>>>(cur, spk);
  k_fused<<<dim3(256), 256, 0, stream>>>(x, spk, wih, bih, gx, whh, bhh,
                                         head_w, head_b, out, flags);
}